// Round 12
// baseline (11561.456 us; speedup 1.0000x reference)
//
#include <hip/hip_runtime.h>
#include <cstdint>
#include <cstddef>

#define Bsz 32
#define Tn  2048
#define Dn  64
#define Hn  512
#define Cn  10
#define NDOM 16   // sync domains (2 batches each)
#define NGB  16   // blocks per domain == waves per block (bijection)
#define UG   32   // hidden units per block
#define BPG  2    // batches per domain
#define NTH  1024 // 16 waves; thread = ksec(5b) | u(5b)
#define RW   1024 // ring words per (parity, domain) = 512 units * 2 batches

__device__ __forceinline__ float sigmoidf_(float v) { return 1.f / (1.f + __expf(-v)); }
__device__ __forceinline__ float tanhf_(float v) {
  const float c = fminf(fmaxf(v, -15.f), 15.f);
  const float e = __expf(-2.f * c);
  return (1.f - e) / (1.f + e);
}

// hT: word j = unit*2 + b. Region [w*64, w*64+64) is PRIVATE to wave w: wave w
//   polls exactly block w's 64 published words (k in [32w,32w+32)) and is the
//   only reader (its ksec pair 2w,2w+1). -> no inter-wave barrier before gh.
// part[parity][wave*64 + row] as float4 {r,z,nx,nh}: writers store one b128 per
//   lane (row = lane, 16B apart -> conflict-free); combiner reads 16 b128
//   (lanes 16B apart -> conflict-free).

__global__ __launch_bounds__(NTH) void gru_main(
    const float* __restrict__ x, const float* __restrict__ w_ih,
    const float* __restrict__ w_hh, const float* __restrict__ b_ih,
    const float* __restrict__ b_hh, float* __restrict__ hs,
    unsigned long long* __restrict__ xch)   // [2][NDOM][RW] tagged ring
{
  const int dom  = blockIdx.x & (NDOM - 1);
  const int g    = blockIdx.x >> 4;         // 0..15
  const int tid  = threadIdx.x;
  const int wave = tid >> 6;
  const int lane = tid & 63;
  const int u    = tid & 31;                // unit within producer block
  const int ksec = tid >> 5;                // 0..31: k-range [ksec*16, ksec*16+16)

  __shared__ float hT[1024];                // wave-private 64-word regions
  __shared__ float xT[2][128];              // [d*2 + b], double buffered
  __shared__ float4 part[2][1024];          // [parity][wave*64+row], 32 KB

  // ---- persistent weights in VGPRs ----
  float wreg[3][16];   // w_hh rows (r,z,n) of unit g*32+u, cols ksec*16..+15
  float wxreg[3][2];   // w_ih cols d = ksec*2, ksec*2+1
  float brz0 = 0.f, brz1 = 0.f, bnx = 0.f, bnh = 0.f;
  #pragma unroll
  for (int i = 0; i < 3; ++i) {
    const int grow = i * Hn + g * UG + u;
    const float4* wp = (const float4*)(w_hh + (size_t)grow * Hn + ksec * 16);
    #pragma unroll
    for (int q = 0; q < 4; ++q) {
      const float4 v = wp[q];
      wreg[i][q * 4 + 0] = v.x; wreg[i][q * 4 + 1] = v.y;
      wreg[i][q * 4 + 2] = v.z; wreg[i][q * 4 + 3] = v.w;
    }
    wxreg[i][0] = w_ih[(size_t)grow * Dn + ksec * 2 + 0];
    wxreg[i][1] = w_ih[(size_t)grow * Dn + ksec * 2 + 1];
    if (i == 0) brz0 = b_ih[grow] + b_hh[grow];
    else if (i == 1) brz1 = b_ih[grow] + b_hh[grow];
    else { bnx = b_ih[grow]; bnh = b_hh[grow]; }
  }

  unsigned long long* const sl0 = xch + (size_t)dom * RW;          // parity 0
  unsigned long long* const sl1 = xch + (size_t)(NDOM + dom) * RW; // parity 1

  const int wword = wave * 64 + lane;       // wave w polls block w's words
  const int ownw  = g * 64 + (lane & 31) * 2 + (lane >> 5);  // publisher map

  hT[tid] = 0.f;                            // h_{-1} = 0
  if (tid < 128) {
    const int bp = tid >> 6, d = tid & 63;
    xT[0][d * 2 + bp] = x[((size_t)(dom * BPG + bp) * Tn + 0) * Dn + d];
  }
  float hold = 0.f;                         // wave15 lane state (u=lane&31, b=lane>>5)
  __syncthreads();

  for (int t = 0; t < Tn; ++t) {
    const int tp = t & 1;
    unsigned long long* const slot = tp ? sl0 : sl1;
    const unsigned long long want = (unsigned long long)t;

    // (1) wave15: combine h_{t-1} from part[tp^1] (16 conflict-free b128),
    //     publish tag t, THEN the hs store (so it has a full step to retire
    //     before the next vmcnt(0) WAW guard -> guard stays free).
    if (t > 0 && wave == 15) {
      const float4* pb = part[tp ^ 1];
      float4 s = pb[lane];
      #pragma unroll
      for (int w = 1; w < 16; ++w) {
        const float4 f = pb[w * 64 + lane];
        s.x += f.x; s.y += f.y; s.z += f.z; s.w += f.w;
      }
      const float r = sigmoidf_(s.x + brz0);
      const float z = sigmoidf_(s.y + brz1);
      const float n = tanhf_(s.z + bnx + r * (s.w + bnh));
      const float h = (1.f - z) * n + z * hold;
      hold = h;
      union { float f; unsigned u32; } cu; cu.f = h;
      // WAW guard: everything outstanding is >= 1 full step old (retired)
      asm volatile("s_waitcnt vmcnt(0)" ::: "memory");
      __hip_atomic_store(slot + ownw, (want << 32) | cu.u32,
                         __ATOMIC_RELAXED, __HIP_MEMORY_SCOPE_AGENT);
      hs[((size_t)(t - 1) * NDOM + dom) * RW + ownw] = h;   // after publish
    }

    // (2) every wave issues its poll load (hides under gx)
    unsigned long long v = 0;
    if (t > 0)
      v = __hip_atomic_load(slot + wword, __ATOMIC_RELAXED, __HIP_MEMORY_SCOPE_AGENT);

    // (3) prefetch x_{t+1}
    float xpre = 0.f;
    if (tid < 128) {
      const int bp = tid >> 6, d = tid & 63;
      const int tn = (t + 1 < Tn) ? (t + 1) : t;
      xpre = x[((size_t)(dom * BPG + bp) * Tn + tn) * Dn + d];
    }

    // (4) gx partials. groups: 0=r, 1=z, 2=n x-part, 3=n h-part
    float acc[4][2];
    #pragma unroll
    for (int i = 0; i < 4; ++i) { acc[i][0] = 0.f; acc[i][1] = 0.f; }
    #pragma unroll
    for (int dd = 0; dd < 2; ++dd) {
      const float2 xb = *(const float2*)&xT[tp][(ksec * 2 + dd) * 2]; // broadcast
      #pragma unroll
      for (int i = 0; i < 3; ++i) {
        const float w = wxreg[i][dd];
        const int gi = (i == 2) ? 2 : i;
        acc[gi][0] += w * xb.x; acc[gi][1] += w * xb.y;
      }
    }

    // (5) tag retry + scatter into wave-private hT region — no barrier needed
    if (t > 0) {
      int gd = 0;
      while ((v >> 32) != want) {
        v = __hip_atomic_load(slot + wword, __ATOMIC_RELAXED, __HIP_MEMORY_SCOPE_AGENT);
        if (++gd > (1 << 17)) break;       // bounded: wrong result beats hang
      }
      union { unsigned u32; float f; } c; c.u32 = (unsigned)v;
      hT[wword] = c.f;
    }

    // (6) stage x_{t+1} (ordered for next step by barrier B)
    if (tid < 128) { const int bp = tid >> 6, d = tid & 63; xT[tp ^ 1][d * 2 + bp] = xpre; }

    // wave-local: own scatter landed before own reads
    asm volatile("s_waitcnt lgkmcnt(0)" ::: "memory");

    // (7) gh partials: broadcast float4 reads from the wave-private region
    {
      const float* hp = hT + ksec * 32;
      #pragma unroll
      for (int k2 = 0; k2 < 8; ++k2) {
        const float4 hv = *(const float4*)(hp + k2 * 4);
        const float a0 = wreg[0][k2 * 2], a1 = wreg[0][k2 * 2 + 1];
        const float b0 = wreg[1][k2 * 2], b1 = wreg[1][k2 * 2 + 1];
        const float c0 = wreg[2][k2 * 2], c1 = wreg[2][k2 * 2 + 1];
        acc[0][0] += a0 * hv.x; acc[0][1] += a0 * hv.y;
        acc[0][0] += a1 * hv.z; acc[0][1] += a1 * hv.w;
        acc[1][0] += b0 * hv.x; acc[1][1] += b0 * hv.y;
        acc[1][0] += b1 * hv.z; acc[1][1] += b1 * hv.w;
        acc[3][0] += c0 * hv.x; acc[3][1] += c0 * hv.y;
        acc[3][0] += c1 * hv.z; acc[3][1] += c1 * hv.w;
      }
    }

    // (8) cross-half reduce (ksec 2w and 2w+1 live in lane and lane^32)
    #pragma unroll
    for (int i = 0; i < 4; ++i) {
      acc[i][0] += __shfl_xor(acc[i][0], 32);
      acc[i][1] += __shfl_xor(acc[i][1], 32);
    }

    // (9) conflict-free b128 partial write: row = lane, batch = lane>>5
    {
      const int b = lane >> 5;
      float4 pv;
      pv.x = acc[0][b]; pv.y = acc[1][b]; pv.z = acc[2][b]; pv.w = acc[3][b];
      part[tp][wave * 64 + lane] = pv;
    }

    // BARRIER B — the only barrier per step (soft: LDS order only)
    asm volatile("s_waitcnt lgkmcnt(0)" ::: "memory");
    __builtin_amdgcn_s_barrier();
    asm volatile("" ::: "memory");
  }

  // epilogue: combine + store h_{Tn-1}
  if (wave == 15) {
    const float4* pb = part[(Tn - 1) & 1];
    float4 s = pb[lane];
    #pragma unroll
    for (int w = 1; w < 16; ++w) {
      const float4 f = pb[w * 64 + lane];
      s.x += f.x; s.y += f.y; s.z += f.z; s.w += f.w;
    }
    const float r = sigmoidf_(s.x + brz0);
    const float z = sigmoidf_(s.y + brz1);
    const float n = tanhf_(s.z + bnx + r * (s.w + bnh));
    const float h = (1.f - z) * n + z * hold;
    hs[((size_t)(Tn - 1) * NDOM + dom) * RW + ownw] = h;
  }
}

__global__ __launch_bounds__(256) void gru_fc(const float* __restrict__ hs,
    const float* __restrict__ w_fc, const float* __restrict__ b_fc,
    float* __restrict__ out)
{
  __shared__ float wfc[Cn * Hn];  // 20 KB
  const int tid = threadIdx.x;
  for (int i = tid; i < Cn * Hn; i += 256) wfc[i] = w_fc[i];
  __syncthreads();
  const int wave = tid >> 6, lane = tid & 63;
  const int bt = blockIdx.x * 4 + wave;        // = b*Tn + t
  const int b = bt >> 11, t = bt & (Tn - 1);
  const int dom = b >> 1, bp = b & 1;
  const float* src = hs + ((size_t)t * NDOM + dom) * RW;
  float acc[Cn];
  #pragma unroll
  for (int c = 0; c < Cn; ++c) acc[c] = 0.f;
  #pragma unroll
  for (int it = 0; it < 8; ++it) {
    const int unit = it * 64 + lane;           // hidden unit 0..511
    const float h = src[unit * 2 + bp];
    #pragma unroll
    for (int c = 0; c < Cn; ++c) acc[c] += h * wfc[c * Hn + unit];
  }
  #pragma unroll
  for (int c = 0; c < Cn; ++c) {
    #pragma unroll
    for (int m = 1; m < 64; m <<= 1) acc[c] += __shfl_xor(acc[c], m);
  }
  if (lane == 0) {
    #pragma unroll
    for (int c = 0; c < Cn; ++c) out[(size_t)bt * Cn + c] = acc[c] + b_fc[c];
  }
}

// Fallback if workspace too small: one block per batch, no inter-block comms.
__global__ __launch_bounds__(512) void gru_fallback(
    const float* __restrict__ x, const float* __restrict__ w_ih,
    const float* __restrict__ w_hh, const float* __restrict__ b_ih,
    const float* __restrict__ b_hh, const float* __restrict__ w_fc,
    const float* __restrict__ b_fc, float* __restrict__ out)
{
  const int b = blockIdx.x;
  const int tid = threadIdx.x;
  __shared__ float hsh[Hn];
  __shared__ float xsh[Dn];
  hsh[tid] = 0.f;
  __syncthreads();
  for (int t = 0; t < Tn; ++t) {
    if (tid < Dn) xsh[tid] = x[((size_t)b * Tn + t) * Dn + tid];
    __syncthreads();
    const int u = tid;
    float gxr = 0.f, gxz = 0.f, gxn = 0.f;
    for (int d = 0; d < Dn; ++d) {
      const float xv = xsh[d];
      gxr += w_ih[(size_t)u * Dn + d] * xv;
      gxz += w_ih[(size_t)(Hn + u) * Dn + d] * xv;
      gxn += w_ih[(size_t)(2 * Hn + u) * Dn + d] * xv;
    }
    float ghr = 0.f, ghz = 0.f, ghn = 0.f;
    for (int k = 0; k < Hn; ++k) {
      const float hv = hsh[k];
      ghr += w_hh[(size_t)u * Hn + k] * hv;
      ghz += w_hh[(size_t)(Hn + u) * Hn + k] * hv;
      ghn += w_hh[(size_t)(2 * Hn + u) * Hn + k] * hv;
    }
    const float r = sigmoidf_(gxr + b_ih[u] + ghr + b_hh[u]);
    const float z = sigmoidf_(gxz + b_ih[Hn + u] + ghz + b_hh[Hn + u]);
    const float n = tanhf(gxn + b_ih[2 * Hn + u] + r * (ghn + b_hh[2 * Hn + u]));
    const float hold = hsh[u];
    __syncthreads();
    hsh[u] = (1.f - z) * n + z * hold;
    __syncthreads();
    if (tid < 320) {
      const int c = tid >> 5, l = tid & 31;
      float a = 0.f;
      for (int kk = 0; kk < 16; ++kk) {
        const int j = l * 16 + kk;
        a += hsh[j] * w_fc[c * Hn + j];
      }
      a += __shfl_xor(a, 1); a += __shfl_xor(a, 2); a += __shfl_xor(a, 4);
      a += __shfl_xor(a, 8); a += __shfl_xor(a, 16);
      if (l == 0) out[((size_t)b * Tn + t) * Cn + c] = a + b_fc[c];
    }
    __syncthreads();
  }
}

extern "C" void kernel_launch(void* const* d_in, const int* in_sizes, int n_in,
                              void* d_out, int out_size, void* d_ws, size_t ws_size,
                              hipStream_t stream) {
  const float* x    = (const float*)d_in[0];
  const float* w_ih = (const float*)d_in[1];
  const float* w_hh = (const float*)d_in[2];
  const float* b_ih = (const float*)d_in[3];
  const float* b_hh = (const float*)d_in[4];
  const float* w_fc = (const float*)d_in[5];
  const float* b_fc = (const float*)d_in[6];
  float* out = (float*)d_out;

  const size_t hs_bytes  = (size_t)Tn * NDOM * RW * sizeof(float);              // 128 MiB
  const size_t xch_bytes = (size_t)2 * NDOM * RW * sizeof(unsigned long long);  // 256 KiB

  if (ws_size >= hs_bytes) {
    float* hs = (float*)d_ws;
    // ring lives in d_out (2.6 MB); gru_fc fully overwrites it after.
    unsigned long long* xchg = (unsigned long long*)d_out;
    hipMemsetAsync(xchg, 0, xch_bytes, stream);  // clear tags each launch (graph-safe)
    hipLaunchKernelGGL(gru_main, dim3(NDOM * NGB), dim3(NTH), 0, stream,
                       x, w_ih, w_hh, b_ih, b_hh, hs, xchg);
    hipLaunchKernelGGL(gru_fc, dim3((Bsz * Tn) / 4), dim3(256), 0, stream,
                       hs, w_fc, b_fc, out);
  } else {
    hipLaunchKernelGGL(gru_fallback, dim3(Bsz), dim3(512), 0, stream,
                       x, w_ih, w_hh, b_ih, b_hh, w_fc, b_fc, out);
  }
}

// Round 13
// 10751.022 us; speedup vs baseline: 1.0754x; 1.0754x over previous
//
#include <hip/hip_runtime.h>
#include <cstdint>
#include <cstddef>

#define Bsz 32
#define Tn  2048
#define Dn  64
#define Hn  512
#define Cn  10
#define NDOM 16   // sync domains (2 batches each)
#define NGB  16   // blocks per domain
#define UG   32   // hidden units per block
#define BPG  2    // batches per domain
#define NTH  1024 // 16 waves; thread = ksec(5b) | u(5b)
#define RW   1024 // ring words per (parity, domain) = 512 units * 2 batches

__device__ __forceinline__ float sigmoidf_(float v) { return 1.f / (1.f + __expf(-v)); }
__device__ __forceinline__ float tanhf_(float v) {
  const float c = fminf(fmaxf(v, -15.f), 15.f);
  const float e = __expf(-2.f * c);
  return (1.f - e) / (1.f + e);
}

// R10 structure (proven 5.47 ms) + conflict-free float4 partials.
// hT: plain [k*2 + b], 1024 floats; broadcast gh reads.
// part[wave*64 + row] (float4 {r,z,nx,nh}, row = b*32+u = lane): each wave
//   writes one contiguous 1KB b128 row-block (conflict-free); wave15's combine
//   reads 16 contiguous 1KB blocks (conflict-free). Single-buffered: combine
//   read (pre-barrier-A) and writes (post-barrier-A) never race.

__global__ __launch_bounds__(NTH) void gru_main(
    const float* __restrict__ x, const float* __restrict__ w_ih,
    const float* __restrict__ w_hh, const float* __restrict__ b_ih,
    const float* __restrict__ b_hh, float* __restrict__ hs,
    unsigned long long* __restrict__ xch)   // [2][NDOM][RW] tagged ring
{
  const int dom  = blockIdx.x & (NDOM - 1);
  const int g    = blockIdx.x >> 4;         // 0..15
  const int tid  = threadIdx.x;
  const int wave = tid >> 6;
  const int lane = tid & 63;
  const int u    = tid & 31;                // unit within block
  const int ksec = tid >> 5;                // 0..31: k-range [ksec*16, ksec*16+16)

  __shared__ float hTb[2][1024];
  __shared__ float xT[2][128];              // [d*2 + b], double buffered
  __shared__ float4 part[1024];             // [wave*64 + row], 16 KB

  // ---- persistent weights in VGPRs: lane owns k = ksec*16 + [0,16) ----
  float wreg[3][16];   // w_hh rows (r,z,n) of unit g*32+u, cols ksec*16..+15
  float wxreg[3][2];   // w_ih cols d = ksec*2, ksec*2+1
  float brz0 = 0.f, brz1 = 0.f, bnx = 0.f, bnh = 0.f;
  #pragma unroll
  for (int i = 0; i < 3; ++i) {
    const int grow = i * Hn + g * UG + u;
    const float4* wp = (const float4*)(w_hh + (size_t)grow * Hn + ksec * 16);
    #pragma unroll
    for (int q = 0; q < 4; ++q) {
      const float4 v = wp[q];
      wreg[i][q * 4 + 0] = v.x; wreg[i][q * 4 + 1] = v.y;
      wreg[i][q * 4 + 2] = v.z; wreg[i][q * 4 + 3] = v.w;
    }
    wxreg[i][0] = w_ih[(size_t)grow * Dn + ksec * 2 + 0];
    wxreg[i][1] = w_ih[(size_t)grow * Dn + ksec * 2 + 1];
    if (i == 0) brz0 = b_ih[grow] + b_hh[grow];
    else if (i == 1) brz1 = b_ih[grow] + b_hh[grow];
    else { bnx = b_ih[grow]; bnh = b_hh[grow]; }
  }

  unsigned long long* const sl0 = xch + (size_t)dom * RW;          // parity 0
  unsigned long long* const sl1 = xch + (size_t)(NDOM + dom) * RW; // parity 1

  // waves 0..14 poll the 960 peer words; wave 15 = combiner/publisher
  const bool dopoll = (wave < 15);
  int wword = 0;
  if (dopoll) {
    const int idx = wave * 64 + lane;
    wword = (idx < g * 64) ? idx : idx + 64;   // skip own 64-word region
  }
  // w15: own ring word j = g*64 + (lane&31)*2 + (lane>>5)  (unit u=lane&31, b=lane>>5)
  const int ownw = g * 64 + (lane & 31) * 2 + (lane >> 5);

  hTb[0][tid & 1023] = 0.f;                  // h0 = 0 (exactly 1024 threads)
  if (tid < 128) {
    const int bp = tid >> 6, d = tid & 63;
    xT[0][d * 2 + bp] = x[((size_t)(dom * BPG + bp) * Tn + 0) * Dn + d];
  }
  float hold = 0.f;                          // w15 lane's own h (u=lane&31, b=lane>>5)
  __syncthreads();

  for (int t = 0; t < Tn; ++t) {
    const int tp = t & 1;
    float* const hT = hTb[tp];
    unsigned long long* const slot = tp ? sl0 : sl1;   // parity (t-1)&1

    // (A1) consumers: issue poll load FIRST (hop hides under gx)
    const unsigned long long want = (unsigned long long)t;
    unsigned long long v = 0;
    if (t > 0 && dopoll)
      v = __hip_atomic_load(slot + wword, __ATOMIC_RELAXED, __HIP_MEMORY_SCOPE_AGENT);

    // (A2) prefetch x_{t+1}
    float xpre = 0.f;
    if (tid < 128) {
      const int bp = tid >> 6, d = tid & 63;
      const int tn = (t + 1 < Tn) ? (t + 1) : t;
      xpre = x[((size_t)(dom * BPG + bp) * Tn + tn) * Dn + d];
    }

    // (A3) gx partials (lane owns d = ksec*2, ksec*2+1)
    // acc groups: 0=r, 1=z, 2=n x-part, 3=n h-part
    float acc[4][2];
    #pragma unroll
    for (int i = 0; i < 4; ++i) { acc[i][0] = 0.f; acc[i][1] = 0.f; }
    #pragma unroll
    for (int dd = 0; dd < 2; ++dd) {
      const float2 xb = *(const float2*)&xT[tp][(ksec * 2 + dd) * 2]; // broadcast
      #pragma unroll
      for (int i = 0; i < 3; ++i) {
        const float w = wxreg[i][dd];
        const int gi = (i == 2) ? 2 : i;
        acc[gi][0] += w * xb.x; acc[gi][1] += w * xb.y;
      }
    }

    if (dopoll) {
      // (A4a) tag check + tight retry, then scatter into hT
      if (t > 0) {
        int gd = 0;
        while ((v >> 32) != want) {
          v = __hip_atomic_load(slot + wword, __ATOMIC_RELAXED, __HIP_MEMORY_SCOPE_AGENT);
          if (++gd > (1 << 17)) break;     // bounded: wrong result beats hang
        }
        union { unsigned u32; float f; } c;
        c.u32 = (unsigned)v;
        hT[wword] = c.f;
      }
    } else if (t > 0) {
      // (A4b) wave 15: sum 16 partials (conflict-free b128) -> combine -> publish
      float4 s = part[lane];
      #pragma unroll
      for (int w = 1; w < 16; ++w) {
        const float4 pv = part[w * 64 + lane];
        s.x += pv.x; s.y += pv.y; s.z += pv.z; s.w += pv.w;
      }
      const float r = sigmoidf_(s.x + brz0);
      const float z = sigmoidf_(s.y + brz1);
      const float n = tanhf_(s.z + bnx + r * (s.w + bnh));
      const float h = (1.f - z) * n + z * hold;
      hold = h;
      hT[ownw] = h;                          // own slice for this step's gh
      union { float f; unsigned u32; } cu; cu.f = h;
      // WAW guard: own 2-step-old ring stores long since retired
      asm volatile("s_waitcnt vmcnt(0)" ::: "memory");
      const unsigned long long w64 = (want << 32) | cu.u32;
      __hip_atomic_store(slot + ownw, w64, __ATOMIC_RELAXED, __HIP_MEMORY_SCOPE_AGENT);
      hs[((size_t)(t - 1) * NDOM + dom) * RW + ownw] = h;
    }

    // (A5) stage x_{t+1}
    if (tid < 128) { const int bp = tid >> 6, d = tid & 63; xT[tp ^ 1][d * 2 + bp] = xpre; }

    // BARRIER A (soft: LDS-order only; global stores stay in flight)
    asm volatile("s_waitcnt lgkmcnt(0)" ::: "memory");
    __builtin_amdgcn_s_barrier();
    asm volatile("" ::: "memory");

    // (B1) gh partials: broadcast float4 reads
    {
      const float* hp = hT + ksec * 32;
      #pragma unroll
      for (int k2 = 0; k2 < 8; ++k2) {
        const float4 hv = *(const float4*)(hp + k2 * 4);
        const float a0 = wreg[0][k2 * 2], a1 = wreg[0][k2 * 2 + 1];
        const float b0 = wreg[1][k2 * 2], b1 = wreg[1][k2 * 2 + 1];
        const float c0 = wreg[2][k2 * 2], c1 = wreg[2][k2 * 2 + 1];
        acc[0][0] += a0 * hv.x; acc[0][1] += a0 * hv.y;
        acc[0][0] += a1 * hv.z; acc[0][1] += a1 * hv.w;
        acc[1][0] += b0 * hv.x; acc[1][1] += b0 * hv.y;
        acc[1][0] += b1 * hv.z; acc[1][1] += b1 * hv.w;
        acc[3][0] += c0 * hv.x; acc[3][1] += c0 * hv.y;
        acc[3][0] += c1 * hv.z; acc[3][1] += c1 * hv.w;
      }
    }

    // (B2) single cross-half reduce (k-halves live in lane and lane^32)
    #pragma unroll
    for (int i = 0; i < 4; ++i) {
      acc[i][0] += __shfl_xor(acc[i][0], 32);
      acc[i][1] += __shfl_xor(acc[i][1], 32);
    }

    // (B3) conflict-free b128 partial write: row = lane (b = lane>>5, u = lane&31)
    {
      const int b = lane >> 5;
      float4 pv;
      pv.x = acc[0][b]; pv.y = acc[1][b]; pv.z = acc[2][b]; pv.w = acc[3][b];
      part[wave * 64 + lane] = pv;
    }

    // BARRIER B (soft)
    asm volatile("s_waitcnt lgkmcnt(0)" ::: "memory");
    __builtin_amdgcn_s_barrier();
    asm volatile("" ::: "memory");
  }

  // epilogue: combine + store h_{Tn-1} (no ring publish needed)
  if (wave == 15) {
    float4 s = part[lane];
    #pragma unroll
    for (int w = 1; w < 16; ++w) {
      const float4 pv = part[w * 64 + lane];
      s.x += pv.x; s.y += pv.y; s.z += pv.z; s.w += pv.w;
    }
    const float r = sigmoidf_(s.x + brz0);
    const float z = sigmoidf_(s.y + brz1);
    const float n = tanhf_(s.z + bnx + r * (s.w + bnh));
    const float h = (1.f - z) * n + z * hold;
    hs[((size_t)(Tn - 1) * NDOM + dom) * RW + ownw] = h;
  }
}

__global__ __launch_bounds__(256) void gru_fc(const float* __restrict__ hs,
    const float* __restrict__ w_fc, const float* __restrict__ b_fc,
    float* __restrict__ out)
{
  __shared__ float wfc[Cn * Hn];  // 20 KB
  const int tid = threadIdx.x;
  for (int i = tid; i < Cn * Hn; i += 256) wfc[i] = w_fc[i];
  __syncthreads();
  const int wave = tid >> 6, lane = tid & 63;
  const int bt = blockIdx.x * 4 + wave;        // = b*Tn + t
  const int b = bt >> 11, t = bt & (Tn - 1);
  const int dom = b >> 1, bp = b & 1;
  const float* src = hs + ((size_t)t * NDOM + dom) * RW;
  float acc[Cn];
  #pragma unroll
  for (int c = 0; c < Cn; ++c) acc[c] = 0.f;
  #pragma unroll
  for (int it = 0; it < 8; ++it) {
    const int unit = it * 64 + lane;           // hidden unit 0..511
    const float h = src[unit * 2 + bp];
    #pragma unroll
    for (int c = 0; c < Cn; ++c) acc[c] += h * wfc[c * Hn + unit];
  }
  #pragma unroll
  for (int c = 0; c < Cn; ++c) {
    #pragma unroll
    for (int m = 1; m < 64; m <<= 1) acc[c] += __shfl_xor(acc[c], m);
  }
  if (lane == 0) {
    #pragma unroll
    for (int c = 0; c < Cn; ++c) out[(size_t)bt * Cn + c] = acc[c] + b_fc[c];
  }
}

// Fallback if workspace too small: one block per batch, no inter-block comms.
__global__ __launch_bounds__(512) void gru_fallback(
    const float* __restrict__ x, const float* __restrict__ w_ih,
    const float* __restrict__ w_hh, const float* __restrict__ b_ih,
    const float* __restrict__ b_hh, const float* __restrict__ w_fc,
    const float* __restrict__ b_fc, float* __restrict__ out)
{
  const int b = blockIdx.x;
  const int tid = threadIdx.x;
  __shared__ float hsh[Hn];
  __shared__ float xsh[Dn];
  hsh[tid] = 0.f;
  __syncthreads();
  for (int t = 0; t < Tn; ++t) {
    if (tid < Dn) xsh[tid] = x[((size_t)b * Tn + t) * Dn + tid];
    __syncthreads();
    const int u = tid;
    float gxr = 0.f, gxz = 0.f, gxn = 0.f;
    for (int d = 0; d < Dn; ++d) {
      const float xv = xsh[d];
      gxr += w_ih[(size_t)u * Dn + d] * xv;
      gxz += w_ih[(size_t)(Hn + u) * Dn + d] * xv;
      gxn += w_ih[(size_t)(2 * Hn + u) * Dn + d] * xv;
    }
    float ghr = 0.f, ghz = 0.f, ghn = 0.f;
    for (int k = 0; k < Hn; ++k) {
      const float hv = hsh[k];
      ghr += w_hh[(size_t)u * Hn + k] * hv;
      ghz += w_hh[(size_t)(Hn + u) * Hn + k] * hv;
      ghn += w_hh[(size_t)(2 * Hn + u) * Hn + k] * hv;
    }
    const float r = sigmoidf_(gxr + b_ih[u] + ghr + b_hh[u]);
    const float z = sigmoidf_(gxz + b_ih[Hn + u] + ghz + b_hh[Hn + u]);
    const float n = tanhf(gxn + b_ih[2 * Hn + u] + r * (ghn + b_hh[2 * Hn + u]));
    const float hold = hsh[u];
    __syncthreads();
    hsh[u] = (1.f - z) * n + z * hold;
    __syncthreads();
    if (tid < 320) {
      const int c = tid >> 5, l = tid & 31;
      float a = 0.f;
      for (int kk = 0; kk < 16; ++kk) {
        const int j = l * 16 + kk;
        a += hsh[j] * w_fc[c * Hn + j];
      }
      a += __shfl_xor(a, 1); a += __shfl_xor(a, 2); a += __shfl_xor(a, 4);
      a += __shfl_xor(a, 8); a += __shfl_xor(a, 16);
      if (l == 0) out[((size_t)b * Tn + t) * Cn + c] = a + b_fc[c];
    }
    __syncthreads();
  }
}

extern "C" void kernel_launch(void* const* d_in, const int* in_sizes, int n_in,
                              void* d_out, int out_size, void* d_ws, size_t ws_size,
                              hipStream_t stream) {
  const float* x    = (const float*)d_in[0];
  const float* w_ih = (const float*)d_in[1];
  const float* w_hh = (const float*)d_in[2];
  const float* b_ih = (const float*)d_in[3];
  const float* b_hh = (const float*)d_in[4];
  const float* w_fc = (const float*)d_in[5];
  const float* b_fc = (const float*)d_in[6];
  float* out = (float*)d_out;

  const size_t hs_bytes  = (size_t)Tn * NDOM * RW * sizeof(float);              // 128 MiB
  const size_t xch_bytes = (size_t)2 * NDOM * RW * sizeof(unsigned long long);  // 256 KiB

  if (ws_size >= hs_bytes) {
    float* hs = (float*)d_ws;
    // ring lives in d_out (2.6 MB); gru_fc fully overwrites it after.
    unsigned long long* xchg = (unsigned long long*)d_out;
    hipMemsetAsync(xchg, 0, xch_bytes, stream);  // clear tags each launch (graph-safe)
    hipLaunchKernelGGL(gru_main, dim3(NDOM * NGB), dim3(NTH), 0, stream,
                       x, w_ih, w_hh, b_ih, b_hh, hs, xchg);
    hipLaunchKernelGGL(gru_fc, dim3((Bsz * Tn) / 4), dim3(256), 0, stream,
                       hs, w_fc, b_fc, out);
  } else {
    hipLaunchKernelGGL(gru_fallback, dim3(Bsz), dim3(512), 0, stream,
                       x, w_ih, w_hh, b_ih, b_hh, w_fc, b_fc, out);
  }
}

// Round 14
// 5484.870 us; speedup vs baseline: 2.1079x; 1.9601x over previous
//
#include <hip/hip_runtime.h>
#include <cstdint>
#include <cstddef>

#define Bsz 32
#define Tn  2048
#define Dn  64
#define Hn  512
#define Cn  10
#define NDOM 16   // sync domains (2 batches each)
#define NGB  16   // blocks per domain
#define UG   32   // hidden units per block
#define BPG  2    // batches per domain
#define NTH  1024 // 16 waves: wave owns 32 k; lane = u(5b) | kh(1b)
#define RW   1024 // ring words per (parity, domain) = 512 units * 2 batches
#define PSTR 68   // partial stride (floats) per (b,u) row: 16 waves * 4 grp + pad

__device__ __forceinline__ float sigmoidf_(float v) { return 1.f / (1.f + __expf(-v)); }
__device__ __forceinline__ float tanhf_(float v) {
  const float c = fminf(fmaxf(v, -15.f), 15.f);
  const float e = __expf(-2.f * c);
  return (1.f - e) / (1.f + e);
}

// hT: plain [k*2 + b], 1024 floats (broadcast reads -> no conflicts, no skew)
// part: [b*32+u][PSTR] ; inner = wave*4 + grp  (grp: 0=r 1=z 2=nx 3=nh)

__global__ __launch_bounds__(NTH) void gru_main(
    const float* __restrict__ x, const float* __restrict__ w_ih,
    const float* __restrict__ w_hh, const float* __restrict__ b_ih,
    const float* __restrict__ b_hh, float* __restrict__ hs,
    unsigned long long* __restrict__ xch)   // [2][NDOM][RW] tagged ring
{
  const int dom  = blockIdx.x & (NDOM - 1);
  const int g    = blockIdx.x >> 4;         // 0..15
  const int tid  = threadIdx.x;
  const int wave = tid >> 6;
  const int lane = tid & 63;
  const int u    = tid & 31;                // unit within block
  const int ksec = tid >> 5;                // 0..31: k-range [ksec*16, ksec*16+16)

  __shared__ float hTb[2][1024];
  __shared__ float xT[2][128];              // [d*2 + b], double buffered
  __shared__ float part[64 * PSTR];         // 17 KB partials

  // ---- persistent weights in VGPRs: lane owns k = ksec*16 + [0,16) ----
  float wreg[3][16];   // w_hh rows (r,z,n) of unit g*32+u, cols ksec*16..+15
  float wxreg[3][2];   // w_ih cols d = ksec*2, ksec*2+1
  float brz0 = 0.f, brz1 = 0.f, bnx = 0.f, bnh = 0.f;
  #pragma unroll
  for (int i = 0; i < 3; ++i) {
    const int grow = i * Hn + g * UG + u;
    const float4* wp = (const float4*)(w_hh + (size_t)grow * Hn + ksec * 16);
    #pragma unroll
    for (int q = 0; q < 4; ++q) {
      const float4 v = wp[q];
      wreg[i][q * 4 + 0] = v.x; wreg[i][q * 4 + 1] = v.y;
      wreg[i][q * 4 + 2] = v.z; wreg[i][q * 4 + 3] = v.w;
    }
    wxreg[i][0] = w_ih[(size_t)grow * Dn + ksec * 2 + 0];
    wxreg[i][1] = w_ih[(size_t)grow * Dn + ksec * 2 + 1];
    if (i == 0) brz0 = b_ih[grow] + b_hh[grow];
    else if (i == 1) brz1 = b_ih[grow] + b_hh[grow];
    else { bnx = b_ih[grow]; bnh = b_hh[grow]; }
  }

  unsigned long long* const sl0 = xch + (size_t)dom * RW;          // parity 0
  unsigned long long* const sl1 = xch + (size_t)(NDOM + dom) * RW; // parity 1

  // waves 0..14 poll the 960 peer words; wave 15 = combiner/publisher
  const bool dopoll = (wave < 15);
  int wword = 0;
  if (dopoll) {
    const int idx = wave * 64 + lane;
    wword = (idx < g * 64) ? idx : idx + 64;   // skip own 64-word region
  }
  // w15: own ring word j = g*64 + (lane&31)*2 + (lane>>5)  (unit u=lane&31, b=lane>>5)
  const int ownw = g * 64 + (lane & 31) * 2 + (lane >> 5);

  hTb[0][tid & 1023] = 0.f;                  // h0 = 0 (exactly 1024 threads)
  if (tid < 128) {
    const int bp = tid >> 6, d = tid & 63;
    xT[0][d * 2 + bp] = x[((size_t)(dom * BPG + bp) * Tn + 0) * Dn + d];
  }
  float hold = 0.f;                          // w15 lane's own h (u=lane&31, b=lane>>5)
  __syncthreads();

  for (int t = 0; t < Tn; ++t) {
    const int tp = t & 1;
    float* const hT = hTb[tp];
    unsigned long long* const slot = tp ? sl0 : sl1;   // parity (t-1)&1

    // (A1) consumers: issue poll load FIRST (hop hides under gx)
    const unsigned long long want = (unsigned long long)t;
    unsigned long long v = 0;
    if (t > 0 && dopoll)
      v = __hip_atomic_load(slot + wword, __ATOMIC_RELAXED, __HIP_MEMORY_SCOPE_AGENT);

    // (A2) prefetch x_{t+1}
    float xpre = 0.f;
    if (tid < 128) {
      const int bp = tid >> 6, d = tid & 63;
      const int tn = (t + 1 < Tn) ? (t + 1) : t;
      xpre = x[((size_t)(dom * BPG + bp) * Tn + tn) * Dn + d];
    }

    // (A3) gx partials (all 16 waves; lane owns d = ksec*2, ksec*2+1)
    // acc groups: 0=r, 1=z, 2=n x-part, 3=n h-part
    float acc[4][2];
    #pragma unroll
    for (int i = 0; i < 4; ++i) { acc[i][0] = 0.f; acc[i][1] = 0.f; }
    #pragma unroll
    for (int dd = 0; dd < 2; ++dd) {
      const float2 xb = *(const float2*)&xT[tp][(ksec * 2 + dd) * 2]; // broadcast
      #pragma unroll
      for (int i = 0; i < 3; ++i) {
        const float w = wxreg[i][dd];
        const int gi = (i == 2) ? 2 : i;
        acc[gi][0] += w * xb.x; acc[gi][1] += w * xb.y;
      }
    }

    if (dopoll) {
      // (A4a) tag check + tight retry, then scatter into hT
      if (t > 0) {
        int gd = 0;
        while ((v >> 32) != want) {
          v = __hip_atomic_load(slot + wword, __ATOMIC_RELAXED, __HIP_MEMORY_SCOPE_AGENT);
          if (++gd > (1 << 17)) break;     // bounded: wrong result beats hang
        }
        union { unsigned u32; float f; } c;
        c.u32 = (unsigned)v;
        hT[wword] = c.f;
      }
    } else if (t > 0) {
      // (A4b) wave 15: sum 16 partials -> combine -> publish h_{t-1}
      const float4* pp = (const float4*)&part[lane * PSTR];
      float4 s = pp[0];
      #pragma unroll
      for (int w = 1; w < 16; ++w) {
        const float4 pv = pp[w];
        s.x += pv.x; s.y += pv.y; s.z += pv.z; s.w += pv.w;
      }
      const float r = sigmoidf_(s.x + brz0);
      const float z = sigmoidf_(s.y + brz1);
      const float n = tanhf_(s.z + bnx + r * (s.w + bnh));
      const float h = (1.f - z) * n + z * hold;
      hold = h;
      hT[ownw] = h;                          // own slice for this step's gh
      union { float f; unsigned u32; } cu; cu.f = h;
      // WAW guard: drain own (2-step-old) ring stores before slot reuse
      asm volatile("s_waitcnt vmcnt(0)" ::: "memory");
      const unsigned long long w64 = (want << 32) | cu.u32;
      __hip_atomic_store(slot + ownw, w64, __ATOMIC_RELAXED, __HIP_MEMORY_SCOPE_AGENT);
      hs[((size_t)(t - 1) * NDOM + dom) * RW + ownw] = h;
    }

    // (A5) stage x_{t+1}
    if (tid < 128) { const int bp = tid >> 6, d = tid & 63; xT[tp ^ 1][d * 2 + bp] = xpre; }

    // BARRIER A (soft: LDS-order only; global stores stay in flight)
    asm volatile("s_waitcnt lgkmcnt(0)" ::: "memory");
    __builtin_amdgcn_s_barrier();
    asm volatile("" ::: "memory");

    // (B1) gh partials: broadcast float4 reads (h[k][0],h[k][1],h[k+1][0],h[k+1][1])
    {
      const float* hp = hT + ksec * 32;
      #pragma unroll
      for (int k2 = 0; k2 < 8; ++k2) {
        const float4 hv = *(const float4*)(hp + k2 * 4);
        const float a0 = wreg[0][k2 * 2], a1 = wreg[0][k2 * 2 + 1];
        const float b0 = wreg[1][k2 * 2], b1 = wreg[1][k2 * 2 + 1];
        const float c0 = wreg[2][k2 * 2], c1 = wreg[2][k2 * 2 + 1];
        acc[0][0] += a0 * hv.x; acc[0][1] += a0 * hv.y;
        acc[0][0] += a1 * hv.z; acc[0][1] += a1 * hv.w;
        acc[1][0] += b0 * hv.x; acc[1][1] += b0 * hv.y;
        acc[1][0] += b1 * hv.z; acc[1][1] += b1 * hv.w;
        acc[3][0] += c0 * hv.x; acc[3][1] += c0 * hv.y;
        acc[3][0] += c1 * hv.z; acc[3][1] += c1 * hv.w;
      }
    }

    // (B2) single cross-half reduce (k-halves live in lane and lane^32)
    #pragma unroll
    for (int i = 0; i < 4; ++i) {
      acc[i][0] += __shfl_xor(acc[i][0], 32);
      acc[i][1] += __shfl_xor(acc[i][1], 32);
    }

    // (B3) write wave partials (deterministic; fully overwritten each step)
    if (lane < 32) {
      float4 p0, p1;
      p0.x = acc[0][0]; p0.y = acc[1][0]; p0.z = acc[2][0]; p0.w = acc[3][0];
      p1.x = acc[0][1]; p1.y = acc[1][1]; p1.z = acc[2][1]; p1.w = acc[3][1];
      *(float4*)&part[u * PSTR + wave * 4]        = p0;   // b = 0
      *(float4*)&part[(32 + u) * PSTR + wave * 4] = p1;   // b = 1
    }

    // BARRIER B (soft)
    asm volatile("s_waitcnt lgkmcnt(0)" ::: "memory");
    __builtin_amdgcn_s_barrier();
    asm volatile("" ::: "memory");
  }

  // epilogue: combine + store h_{Tn-1} (no ring publish needed)
  if (wave == 15) {
    const float4* pp = (const float4*)&part[lane * PSTR];
    float4 s = pp[0];
    #pragma unroll
    for (int w = 1; w < 16; ++w) {
      const float4 pv = pp[w];
      s.x += pv.x; s.y += pv.y; s.z += pv.z; s.w += pv.w;
    }
    const float r = sigmoidf_(s.x + brz0);
    const float z = sigmoidf_(s.y + brz1);
    const float n = tanhf_(s.z + bnx + r * (s.w + bnh));
    const float h = (1.f - z) * n + z * hold;
    hs[((size_t)(Tn - 1) * NDOM + dom) * RW + ownw] = h;
  }
}

__global__ __launch_bounds__(256) void gru_fc(const float* __restrict__ hs,
    const float* __restrict__ w_fc, const float* __restrict__ b_fc,
    float* __restrict__ out)
{
  __shared__ float wfc[Cn * Hn];  // 20 KB
  const int tid = threadIdx.x;
  for (int i = tid; i < Cn * Hn; i += 256) wfc[i] = w_fc[i];
  __syncthreads();
  const int wave = tid >> 6, lane = tid & 63;
  const int bt = blockIdx.x * 4 + wave;        // = b*Tn + t
  const int b = bt >> 11, t = bt & (Tn - 1);
  const int dom = b >> 1, bp = b & 1;
  const float* src = hs + ((size_t)t * NDOM + dom) * RW;
  float acc[Cn];
  #pragma unroll
  for (int c = 0; c < Cn; ++c) acc[c] = 0.f;
  #pragma unroll
  for (int it = 0; it < 8; ++it) {
    const int unit = it * 64 + lane;           // hidden unit 0..511
    const float h = src[unit * 2 + bp];
    #pragma unroll
    for (int c = 0; c < Cn; ++c) acc[c] += h * wfc[c * Hn + unit];
  }
  #pragma unroll
  for (int c = 0; c < Cn; ++c) {
    #pragma unroll
    for (int m = 1; m < 64; m <<= 1) acc[c] += __shfl_xor(acc[c], m);
  }
  if (lane == 0) {
    #pragma unroll
    for (int c = 0; c < Cn; ++c) out[(size_t)bt * Cn + c] = acc[c] + b_fc[c];
  }
}

// Fallback if workspace too small: one block per batch, no inter-block comms.
__global__ __launch_bounds__(512) void gru_fallback(
    const float* __restrict__ x, const float* __restrict__ w_ih,
    const float* __restrict__ w_hh, const float* __restrict__ b_ih,
    const float* __restrict__ b_hh, const float* __restrict__ w_fc,
    const float* __restrict__ b_fc, float* __restrict__ out)
{
  const int b = blockIdx.x;
  const int tid = threadIdx.x;
  __shared__ float hsh[Hn];
  __shared__ float xsh[Dn];
  hsh[tid] = 0.f;
  __syncthreads();
  for (int t = 0; t < Tn; ++t) {
    if (tid < Dn) xsh[tid] = x[((size_t)b * Tn + t) * Dn + tid];
    __syncthreads();
    const int u = tid;
    float gxr = 0.f, gxz = 0.f, gxn = 0.f;
    for (int d = 0; d < Dn; ++d) {
      const float xv = xsh[d];
      gxr += w_ih[(size_t)u * Dn + d] * xv;
      gxz += w_ih[(size_t)(Hn + u) * Dn + d] * xv;
      gxn += w_ih[(size_t)(2 * Hn + u) * Dn + d] * xv;
    }
    float ghr = 0.f, ghz = 0.f, ghn = 0.f;
    for (int k = 0; k < Hn; ++k) {
      const float hv = hsh[k];
      ghr += w_hh[(size_t)u * Hn + k] * hv;
      ghz += w_hh[(size_t)(Hn + u) * Hn + k] * hv;
      ghn += w_hh[(size_t)(2 * Hn + u) * Hn + k] * hv;
    }
    const float r = sigmoidf_(gxr + b_ih[u] + ghr + b_hh[u]);
    const float z = sigmoidf_(gxz + b_ih[Hn + u] + ghz + b_hh[Hn + u]);
    const float n = tanhf(gxn + b_ih[2 * Hn + u] + r * (ghn + b_hh[2 * Hn + u]));
    const float hold = hsh[u];
    __syncthreads();
    hsh[u] = (1.f - z) * n + z * hold;
    __syncthreads();
    if (tid < 320) {
      const int c = tid >> 5, l = tid & 31;
      float a = 0.f;
      for (int kk = 0; kk < 16; ++kk) {
        const int j = l * 16 + kk;
        a += hsh[j] * w_fc[c * Hn + j];
      }
      a += __shfl_xor(a, 1); a += __shfl_xor(a, 2); a += __shfl_xor(a, 4);
      a += __shfl_xor(a, 8); a += __shfl_xor(a, 16);
      if (l == 0) out[((size_t)b * Tn + t) * Cn + c] = a + b_fc[c];
    }
    __syncthreads();
  }
}

extern "C" void kernel_launch(void* const* d_in, const int* in_sizes, int n_in,
                              void* d_out, int out_size, void* d_ws, size_t ws_size,
                              hipStream_t stream) {
  const float* x    = (const float*)d_in[0];
  const float* w_ih = (const float*)d_in[1];
  const float* w_hh = (const float*)d_in[2];
  const float* b_ih = (const float*)d_in[3];
  const float* b_hh = (const float*)d_in[4];
  const float* w_fc = (const float*)d_in[5];
  const float* b_fc = (const float*)d_in[6];
  float* out = (float*)d_out;

  const size_t hs_bytes  = (size_t)Tn * NDOM * RW * sizeof(float);              // 128 MiB
  const size_t xch_bytes = (size_t)2 * NDOM * RW * sizeof(unsigned long long);  // 256 KiB

  if (ws_size >= hs_bytes) {
    float* hs = (float*)d_ws;
    // ring lives in d_out (2.6 MB); gru_fc fully overwrites it after.
    unsigned long long* xchg = (unsigned long long*)d_out;
    hipMemsetAsync(xchg, 0, xch_bytes, stream);  // clear tags each launch (graph-safe)
    hipLaunchKernelGGL(gru_main, dim3(NDOM * NGB), dim3(NTH), 0, stream,
                       x, w_ih, w_hh, b_ih, b_hh, hs, xchg);
    hipLaunchKernelGGL(gru_fc, dim3((Bsz * Tn) / 4), dim3(256), 0, stream,
                       hs, w_fc, b_fc, out);
  } else {
    hipLaunchKernelGGL(gru_fallback, dim3(Bsz), dim3(512), 0, stream,
                       x, w_ih, w_hh, b_ih, b_hh, w_fc, b_fc, out);
  }
}